// Round 1
// baseline (73.113 us; speedup 1.0000x reference)
//
#include <hip/hip_runtime.h>
#include <hip/hip_bf16.h>

typedef __attribute__((ext_vector_type(8))) short short8;
typedef __attribute__((ext_vector_type(4))) float f32x4;

#define NROWS   262144
#define ODIM    64
#define KSTEPS  24            // K = 768 = 24 * 32
#define NWAVES  8
#define NBLOCKS 256
#define INV2PI  0.15915494309189535f

__device__ __forceinline__ float cos2pi(float f){ float r; asm("v_cos_f32 %0, %1" : "=v"(r) : "v"(f)); return r; }
__device__ __forceinline__ float sin2pi(float f){ float r; asm("v_sin_f32 %0, %1" : "=v"(r) : "v"(f)); return r; }

__device__ __forceinline__ short bf16_of(float f){
    union { __hip_bfloat16 h; short s; } u;
    u.h = __float2bfloat16(f);
    return u.s;
}

// out[b,o] = sum_k F[b,k] * W[o,k], F[:, k<384]=cos((g+1)x_i), F[:, k>=384]=sin(...)
// k = branch*384 + i*128 + g ; W[o,k] = coeffs[branch, o, i, g]
extern "C" __global__ void __launch_bounds__(512, 2)
fourier_mfma(const float* __restrict__ x,
             const float* __restrict__ coeffs,
             const float* __restrict__ bias,
             float* __restrict__ out)
{
    // Fragment-ordered bf16 weights: [ks][nt][lane] -> 8 bf16 (one ds_read_b128)
    __shared__ short8 Wlds[KSTEPS * 4 * 64];   // 98304 B

    const int tid = threadIdx.x;

    // ---- one-time weight staging: fp32 global -> bf16 fragments in LDS ----
    for (int fl = tid; fl < KSTEPS*4*64; fl += 512) {
        const int ks = fl >> 8;
        const int nt = (fl >> 6) & 3;
        const int ln = fl & 63;
        const int o  = nt*16 + (ln & 15);   // B-frag: col = lane & 15
        const int kg = ln >> 4;             // k sub-band = 4*(lane>>4)
        union { short8 v; short s[8]; } fr;
        #pragma unroll
        for (int h = 0; h < 2; ++h) {
            const int kb  = ks*32 + h*16;          // 16-aligned k-block
            const int br  = (kb >= 384) ? 1 : 0;
            const int rem = kb - br*384;
            const int ii  = rem >> 7;
            const int g0  = (rem & 127) + kg*4;
            const float* wp = coeffs + (((br*ODIM + o)*3 + ii) << 7) + g0;
            #pragma unroll
            for (int j = 0; j < 4; ++j) fr.s[h*4 + j] = bf16_of(wp[j]);
        }
        Wlds[fl] = fr.v;
    }
    __syncthreads();

    const int lane = tid & 63;
    const int wid  = tid >> 6;
    const int mrow = lane & 15;     // A-frag row within 16-row tile
    const int kgrp = lane >> 4;     // k sub-band / D-row group
    const float lane_off = (float)(4*kgrp);

    float bcol[4];
    #pragma unroll
    for (int nt = 0; nt < 4; ++nt) bcol[nt] = bias[nt*16 + mrow];

    const int gw = blockIdx.x * NWAVES + wid;      // 0..2047

    for (int unit = gw; unit < NROWS/64; unit += NBLOCKS*NWAVES) {
        const int base = unit * 64;

        // Per-row trig basis: angle in revolutions; x in [0,1) rad so no reduction needed
        float xrev[4][3], cb[4][3], sb[4][3];
        #pragma unroll
        for (int r = 0; r < 4; ++r) {
            const int row = base + r*16 + mrow;
            #pragma unroll
            for (int i = 0; i < 3; ++i) {
                const float rv = x[row*3 + i] * INV2PI;
                xrev[r][i] = rv;
                cb[r][i]   = cos2pi(rv);
                sb[r][i]   = sin2pi(rv);
            }
        }

        f32x4 acc[4][4];
        #pragma unroll
        for (int r = 0; r < 4; ++r)
            #pragma unroll
            for (int nt = 0; nt < 4; ++nt)
                acc[r][nt] = (f32x4){0.f, 0.f, 0.f, 0.f};

        for (int ks = 0; ks < KSTEPS; ++ks) {
            const int br = (ks >= 12) ? 1 : 0;   // uniform per k-step (384 boundary = ks 12)
            short8 afrag[4];
            #pragma unroll
            for (int r = 0; r < 4; ++r) {
                union { short8 v; short s[8]; } fr;
                #pragma unroll
                for (int h = 0; h < 2; ++h) {
                    const int kb   = ks*32 + h*16;
                    const int rem  = kb - br*384;
                    const int ii   = rem >> 7;
                    const float g1 = (float)((rem & 127) + 1);
                    const float xr = xrev[r][ii];
                    const float harm = g1 + lane_off;       // harmonic number
                    const float rv = harm * xr;             // revolutions
                    const float f  = rv - floorf(rv);
                    const float c0 = cos2pi(f);
                    const float s0 = sin2pi(f);
                    const float cv = cb[r][ii], sv = sb[r][ii];
                    const float c1 = c0*cv - s0*sv;
                    const float s1 = s0*cv + c0*sv;
                    const float c2 = c1*cv - s1*sv;
                    const float s2 = s1*cv + c1*sv;
                    const float c3 = c2*cv - s2*sv;
                    const float s3 = s2*cv + c2*sv;
                    if (br) {
                        fr.s[h*4+0] = bf16_of(s0);
                        fr.s[h*4+1] = bf16_of(s1);
                        fr.s[h*4+2] = bf16_of(s2);
                        fr.s[h*4+3] = bf16_of(s3);
                    } else {
                        fr.s[h*4+0] = bf16_of(c0);
                        fr.s[h*4+1] = bf16_of(c1);
                        fr.s[h*4+2] = bf16_of(c2);
                        fr.s[h*4+3] = bf16_of(c3);
                    }
                }
                afrag[r] = fr.v;
            }
            #pragma unroll
            for (int nt = 0; nt < 4; ++nt) {
                const short8 bfrag = Wlds[(ks*4 + nt)*64 + lane];
                #pragma unroll
                for (int r = 0; r < 4; ++r)
                    acc[r][nt] = __builtin_amdgcn_mfma_f32_16x16x32_bf16(afrag[r], bfrag, acc[r][nt], 0, 0, 0);
            }
        }

        // D layout: col = lane&15, row = 4*(lane>>4) + reg   [m89-verified]
        #pragma unroll
        for (int r = 0; r < 4; ++r) {
            const int row0 = base + r*16 + kgrp*4;
            #pragma unroll
            for (int nt = 0; nt < 4; ++nt) {
                #pragma unroll
                for (int q = 0; q < 4; ++q) {
                    out[(row0 + q)*ODIM + nt*16 + mrow] = acc[r][nt][q] + bcol[nt];
                }
            }
        }
    }
}

extern "C" void kernel_launch(void* const* d_in, const int* in_sizes, int n_in,
                              void* d_out, int out_size, void* d_ws, size_t ws_size,
                              hipStream_t stream) {
    const float* x      = (const float*)d_in[0];
    const float* coeffs = (const float*)d_in[1];
    const float* bias   = (const float*)d_in[2];
    float* out = (float*)d_out;
    (void)in_sizes; (void)n_in; (void)out_size; (void)d_ws; (void)ws_size;
    hipLaunchKernelGGL(fourier_mfma, dim3(NBLOCKS), dim3(512), 0, stream, x, coeffs, bias, out);
}

// Round 2
// 47.984 us; speedup vs baseline: 1.5237x; 1.5237x over previous
//
#include <hip/hip_runtime.h>
#include <hip/hip_bf16.h>

typedef __attribute__((ext_vector_type(8))) short short8;
typedef __attribute__((ext_vector_type(4))) float f32x4;

#define NROWS   262144
#define ODIM    64
#define KSTEPS  24            // K = 768 = 24 * 32
#define NBLOCKS 256
#define TPB     1024          // 16 waves -> 4 waves/SIMD at 1 block/CU
#define INV2PI  0.15915494309189535f

__device__ __forceinline__ float cos2pi(float f){ float r; asm("v_cos_f32 %0, %1" : "=v"(r) : "v"(f)); return r; }
__device__ __forceinline__ float sin2pi(float f){ float r; asm("v_sin_f32 %0, %1" : "=v"(r) : "v"(f)); return r; }

__device__ __forceinline__ short bf16_of(float f){
    union { __hip_bfloat16 h; short s; } u;
    u.h = __float2bfloat16(f);
    return u.s;
}

// out[b,o] = sum_k F[b,k] * W[o,k]; k = br*384 + i*128 + g
// F[:,k] = cos((g+1)x_i) for br=0, sin((g+1)x_i) for br=1; W[o,k]=coeffs[br,o,i,g]
// Pairing: ks_c in [0,12) (cos) shares harmonics with ks_c+12 (sin).
extern "C" __global__ void __launch_bounds__(TPB, 4)
fourier_mfma(const float* __restrict__ x,
             const float* __restrict__ coeffs,
             const float* __restrict__ bias,
             float* __restrict__ out)
{
    // Fragment-ordered bf16 weights: [ks][nt][lane] -> 8 bf16 (one ds_read_b128)
    __shared__ short8 Wlds[KSTEPS * 4 * 64];   // 98304 B

    const int tid = threadIdx.x;

    // ---- one-time weight staging: fp32 global -> bf16 fragments in LDS ----
    for (int fl = tid; fl < KSTEPS*4*64; fl += TPB) {
        const int ks = fl >> 8;
        const int nt = (fl >> 6) & 3;
        const int ln = fl & 63;
        const int o  = nt*16 + (ln & 15);   // B-frag: col = lane & 15
        const int kg = ln >> 4;             // k sub-band = 4*(lane>>4)
        union { short8 v; short s[8]; } fr;
        #pragma unroll
        for (int h = 0; h < 2; ++h) {
            const int kb  = ks*32 + h*16;
            const int br  = (kb >= 384) ? 1 : 0;
            const int rem = kb - br*384;
            const int ii  = rem >> 7;
            const int g0  = (rem & 127) + kg*4;
            const float* wp = coeffs + (((br*ODIM + o)*3 + ii) << 7) + g0;
            #pragma unroll
            for (int j = 0; j < 4; ++j) fr.s[h*4 + j] = bf16_of(wp[j]);
        }
        Wlds[fl] = fr.v;
    }
    __syncthreads();

    const int lane = tid & 63;
    const int wid  = tid >> 6;
    const int mrow = lane & 15;     // A-frag row within 16-row tile
    const int kgrp = lane >> 4;     // k sub-band / D-row group
    const float hs = (float)(4*kgrp + 1);   // lane's starting harmonic in each 16-block

    float bcol[4];
    #pragma unroll
    for (int nt = 0; nt < 4; ++nt) bcol[nt] = bias[nt*16 + mrow];

    const int unit = blockIdx.x * 16 + wid;   // 256*16 = 4096 units, exactly NROWS/64
    const int base = unit * 64;

    // Two sequential 32-row passes to keep VGPRs under the 4-wave/SIMD cap.
    for (int rg = 0; rg < 2; ++rg) {
        f32x4 acc[2][4];
        #pragma unroll
        for (int rr = 0; rr < 2; ++rr)
            #pragma unroll
            for (int nt = 0; nt < 4; ++nt)
                acc[rr][nt] = (f32x4){0.f, 0.f, 0.f, 0.f};

        for (int i = 0; i < 3; ++i) {
            // Per-(row,i) rotation constants + chain state.
            float cv[2], sv[2], c16[2], s16[2], stc[2], sts[2];
            #pragma unroll
            for (int rr = 0; rr < 2; ++rr) {
                const int row = base + (rg*2 + rr)*16 + mrow;
                const float xr = x[row*3 + i] * INV2PI;     // < 0.1592 rev
                cv[rr] = cos2pi(xr);  sv[rr] = sin2pi(xr);  // rotate by 1*x
                float t = 16.f * xr;  t -= floorf(t);
                c16[rr] = cos2pi(t);  s16[rr] = sin2pi(t);  // rotate by 16*x
                float u = hs * xr;    u -= floorf(u);
                stc[rr] = cos2pi(u);  sts[rr] = sin2pi(u);  // state: harmonic 4*kgrp+1
            }

            for (int kc = 0; kc < 4; ++kc) {
                const int ks_c = i*4 + kc;                 // cos k-step; sin = ks_c+12
                union { short8 v; short s[8]; } fc[2], fs[2];
                #pragma unroll
                for (int h = 0; h < 2; ++h) {
                    #pragma unroll
                    for (int rr = 0; rr < 2; ++rr) {
                        float c = stc[rr], s = sts[rr];
                        fc[rr].s[h*4+0] = bf16_of(c);
                        fs[rr].s[h*4+0] = bf16_of(s);
                        #pragma unroll
                        for (int j = 1; j < 4; ++j) {
                            const float cn = c*cv[rr] - s*sv[rr];
                            const float sn = s*cv[rr] + c*sv[rr];
                            c = cn; s = sn;
                            fc[rr].s[h*4+j] = bf16_of(c);
                            fs[rr].s[h*4+j] = bf16_of(s);
                        }
                        // advance chain state by 16*x for next 16-block
                        const float nc = stc[rr]*c16[rr] - sts[rr]*s16[rr];
                        const float ns = sts[rr]*c16[rr] + stc[rr]*s16[rr];
                        stc[rr] = nc; sts[rr] = ns;
                    }
                }
                #pragma unroll
                for (int nt = 0; nt < 4; ++nt) {
                    const short8 bc = Wlds[(ks_c*4 + nt)*64 + lane];
                    const short8 bs = Wlds[((ks_c + 12)*4 + nt)*64 + lane];
                    #pragma unroll
                    for (int rr = 0; rr < 2; ++rr) {
                        acc[rr][nt] = __builtin_amdgcn_mfma_f32_16x16x32_bf16(fc[rr].v, bc, acc[rr][nt], 0, 0, 0);
                        acc[rr][nt] = __builtin_amdgcn_mfma_f32_16x16x32_bf16(fs[rr].v, bs, acc[rr][nt], 0, 0, 0);
                    }
                }
            }
        }

        // Epilogue for this 32-row pass.
        // D layout: col = lane&15, row = 4*(lane>>4) + reg   [m89-verified]
        #pragma unroll
        for (int rr = 0; rr < 2; ++rr) {
            const int row0 = base + (rg*2 + rr)*16 + kgrp*4;
            #pragma unroll
            for (int nt = 0; nt < 4; ++nt) {
                #pragma unroll
                for (int q = 0; q < 4; ++q) {
                    out[(row0 + q)*ODIM + nt*16 + mrow] = acc[rr][nt][q] + bcol[nt];
                }
            }
        }
    }
}

extern "C" void kernel_launch(void* const* d_in, const int* in_sizes, int n_in,
                              void* d_out, int out_size, void* d_ws, size_t ws_size,
                              hipStream_t stream) {
    const float* x      = (const float*)d_in[0];
    const float* coeffs = (const float*)d_in[1];
    const float* bias   = (const float*)d_in[2];
    float* out = (float*)d_out;
    (void)in_sizes; (void)n_in; (void)out_size; (void)d_ws; (void)ws_size;
    hipLaunchKernelGGL(fourier_mfma, dim3(NBLOCKS), dim3(TPB), 0, stream, x, coeffs, bias, out);
}

// Round 3
// 41.848 us; speedup vs baseline: 1.7471x; 1.1466x over previous
//
#include <hip/hip_runtime.h>
#include <hip/hip_bf16.h>

typedef __attribute__((ext_vector_type(8))) short short8;
typedef __attribute__((ext_vector_type(4))) float f32x4;
typedef __attribute__((ext_vector_type(2))) float f32x2;

#define NROWS   262144
#define ODIM    64
#define KSTEPS  24            // K = 768 = 24 * 32
#define NBLOCKS 256
#define TPB     1024          // 16 waves; LDS caps us at 1 block/CU -> 4 waves/SIMD
#define INV2PI  0.15915494309189535f

__device__ __forceinline__ float cos2pi(float f){ float r; asm("v_cos_f32 %0, %1" : "=v"(r) : "v"(f)); return r; }
__device__ __forceinline__ float sin2pi(float f){ float r; asm("v_sin_f32 %0, %1" : "=v"(r) : "v"(f)); return r; }

__device__ __forceinline__ short bf16_of(float f){
    union { __hip_bfloat16 h; short s; } u;
    u.h = __float2bfloat16(f);
    return u.s;
}

// out[b,o] = sum_k F[b,k] * W[o,k]; k = br*384 + i*128 + g
// F[:,k] = cos((g+1)x_i) for br=0, sin((g+1)x_i) for br=1; W[o,k]=coeffs[br,o,i,g]
// cos k-step kk (0..11) pairs with sin k-step kk+12 (identical harmonics).
extern "C" __global__ void __launch_bounds__(TPB, 4)
fourier_mfma(const float* __restrict__ x,
             const float* __restrict__ coeffs,
             const float* __restrict__ bias,
             float* __restrict__ out)
{
    // Fragment-ordered bf16 weights: [ks][nt][lane] -> 8 bf16 (one ds_read_b128)
    __shared__ short8 Wlds[KSTEPS * 4 * 64];   // 98304 B

    const int tid = threadIdx.x;

    // ---- one-time weight staging: fp32 global -> bf16 fragments in LDS ----
    for (int fl = tid; fl < KSTEPS*4*64; fl += TPB) {
        const int ks = fl >> 8;
        const int nt = (fl >> 6) & 3;
        const int ln = fl & 63;
        const int o  = nt*16 + (ln & 15);   // B-frag: col = lane & 15
        const int kg = ln >> 4;             // k sub-band = 4*(lane>>4)
        union { short8 v; short s[8]; } fr;
        #pragma unroll
        for (int h = 0; h < 2; ++h) {
            const int kb  = ks*32 + h*16;
            const int br  = (kb >= 384) ? 1 : 0;
            const int rem = kb - br*384;
            const int ii  = rem >> 7;
            const int g0  = (rem & 127) + kg*4;
            const float* wp = coeffs + (((br*ODIM + o)*3 + ii) << 7) + g0;
            #pragma unroll
            for (int j = 0; j < 4; ++j) fr.s[h*4 + j] = bf16_of(wp[j]);
        }
        Wlds[fl] = fr.v;
    }
    __syncthreads();

    const int lane = tid & 63;
    const int wid  = tid >> 6;
    const int mrow = lane & 15;     // A-frag row within 16-row tile
    const int kgrp = lane >> 4;     // k sub-band / D-row group
    const float hs = (float)(4*kgrp + 1);   // lane's starting harmonic per 16-block

    float bcol[4];
    #pragma unroll
    for (int nt = 0; nt < 4; ++nt) bcol[nt] = bias[nt*16 + mrow];

    const int unit = blockIdx.x * 16 + wid;   // 256*16 = 4096 units = NROWS/64
    const int base = unit * 64;

    // Two sequential 32-row passes; each pass handles a packed row-pair (rr=0,1).
    for (int rg = 0; rg < 2; ++rg) {
        const int rowA = base + (rg*2 + 0)*16 + mrow;
        const int rowB = base + (rg*2 + 1)*16 + mrow;

        // Preload x (revolutions) for both rows, all 3 input dims.
        f32x2 xr[3];
        #pragma unroll
        for (int i = 0; i < 3; ++i)
            xr[i] = (f32x2){ x[rowA*3 + i] * INV2PI, x[rowB*3 + i] * INV2PI };

        f32x4 acc[2][4];
        #pragma unroll
        for (int rr = 0; rr < 2; ++rr)
            #pragma unroll
            for (int nt = 0; nt < 4; ++nt)
                acc[rr][nt] = (f32x4){0.f, 0.f, 0.f, 0.f};

        f32x2 cvp, svp, c16p, s16p, stc, sts;

        #pragma unroll
        for (int kk = 0; kk < 12; ++kk) {          // cos k-step; sin is kk+12
            // -- early-issue this step's 8 b-frags (latency hides under feature gen)
            short8 bfr[8];                          // [branch*4 + nt], all static idx
            #pragma unroll
            for (int nt = 0; nt < 4; ++nt) {
                bfr[nt]     = Wlds[(kk*4 + nt)*64 + lane];
                bfr[4 + nt] = Wlds[((kk + 12)*4 + nt)*64 + lane];
            }

            if ((kk & 3) == 0) {                    // per-input-dim trig setup
                const int i = kk >> 2;
                const f32x2 a = xr[i];
                cvp = (f32x2){ cos2pi(a.x), cos2pi(a.y) };   // rotate by 1*x
                svp = (f32x2){ sin2pi(a.x), sin2pi(a.y) };
                f32x2 t = (f32x2){ 16.f*a.x, 16.f*a.y };
                t.x -= floorf(t.x); t.y -= floorf(t.y);
                c16p = (f32x2){ cos2pi(t.x), cos2pi(t.y) };  // rotate by 16*x
                s16p = (f32x2){ sin2pi(t.x), sin2pi(t.y) };
                f32x2 u = (f32x2){ hs*a.x, hs*a.y };
                u.x -= floorf(u.x); u.y -= floorf(u.y);
                stc = (f32x2){ cos2pi(u.x), cos2pi(u.y) };   // state: harmonic 4*kgrp+1
                sts = (f32x2){ sin2pi(u.x), sin2pi(u.y) };
            }

            union { short8 v; short s[8]; } fc[2], fs[2];
            #pragma unroll
            for (int h = 0; h < 2; ++h) {
                f32x2 c = stc, s = sts;
                fc[0].s[h*4] = bf16_of(c.x); fc[1].s[h*4] = bf16_of(c.y);
                fs[0].s[h*4] = bf16_of(s.x); fs[1].s[h*4] = bf16_of(s.y);
                #pragma unroll
                for (int j = 1; j < 4; ++j) {
                    const f32x2 cn = c*cvp - s*svp;   // packed dual-FMA rotation
                    const f32x2 sn = s*cvp + c*svp;
                    c = cn; s = sn;
                    fc[0].s[h*4+j] = bf16_of(c.x); fc[1].s[h*4+j] = bf16_of(c.y);
                    fs[0].s[h*4+j] = bf16_of(s.x); fs[1].s[h*4+j] = bf16_of(s.y);
                }
                const f32x2 nc = stc*c16p - sts*s16p; // advance state by 16*x
                const f32x2 ns = sts*c16p + stc*s16p;
                stc = nc; sts = ns;
            }

            #pragma unroll
            for (int nt = 0; nt < 4; ++nt) {
                #pragma unroll
                for (int rr = 0; rr < 2; ++rr) {
                    acc[rr][nt] = __builtin_amdgcn_mfma_f32_16x16x32_bf16(fc[rr].v, bfr[nt],     acc[rr][nt], 0, 0, 0);
                    acc[rr][nt] = __builtin_amdgcn_mfma_f32_16x16x32_bf16(fs[rr].v, bfr[4 + nt], acc[rr][nt], 0, 0, 0);
                }
            }
        }

        // Epilogue. D layout: col = lane&15, row = 4*(lane>>4) + reg  [m89-verified]
        #pragma unroll
        for (int rr = 0; rr < 2; ++rr) {
            const int row0 = base + (rg*2 + rr)*16 + kgrp*4;
            #pragma unroll
            for (int nt = 0; nt < 4; ++nt) {
                #pragma unroll
                for (int q = 0; q < 4; ++q) {
                    out[(row0 + q)*ODIM + nt*16 + mrow] = acc[rr][nt][q] + bcol[nt];
                }
            }
        }
    }
}

extern "C" void kernel_launch(void* const* d_in, const int* in_sizes, int n_in,
                              void* d_out, int out_size, void* d_ws, size_t ws_size,
                              hipStream_t stream) {
    const float* x      = (const float*)d_in[0];
    const float* coeffs = (const float*)d_in[1];
    const float* bias   = (const float*)d_in[2];
    float* out = (float*)d_out;
    (void)in_sizes; (void)n_in; (void)out_size; (void)d_ws; (void)ws_size;
    hipLaunchKernelGGL(fourier_mfma, dim3(NBLOCKS), dim3(TPB), 0, stream, x, coeffs, bias, out);
}